// Round 4
// baseline (652.897 us; speedup 1.0000x reference)
//
#include <hip/hip_runtime.h>

#define DEVINL __device__ __forceinline__

typedef __attribute__((ext_vector_type(8))) short          s16x8;
typedef __attribute__((ext_vector_type(8))) unsigned short u16x8;
typedef __attribute__((ext_vector_type(4))) unsigned short u16x4;
typedef __attribute__((ext_vector_type(4))) float          f32x4;

DEVINL unsigned short f2b(float f) {
    union { float f; unsigned int u; } c; c.f = f;
    return (unsigned short)((c.u + 0x7FFFu + ((c.u >> 16) & 1u)) >> 16);
}
DEVINL f32x4 mfma16(s16x8 a, s16x8 b, f32x4 c) {
    return __builtin_amdgcn_mfma_f32_16x16x32_bf16(a, b, c, 0, 0, 0);
}

// ---- bf16 weight cache in d_ws (concatenated, row-major as in HBM) ----
#define QKV_ELEMS 110592
#define KV_ELEMS  73728
#define M1_ELEMS  73728
#define M2_ELEMS  36864
#define PW_ELEMS  36864
#define O_QKV 0
#define O_KV  110592
#define O_M1  184320
#define O_M2  258048
#define O_PW  294912
#define WB_ELEMS 331776
#define WB_BYTES (WB_ELEMS * 2)

// ---- LDS layout (ushort elements). Region lifetimes:
//  R1 (64x200=12800): x -> Q -> P(attn1) -> y -> P(attn2) -> M1
//  R2 (64x200=12800): K -> K2 -> CAT[cols 0..)   -> M2
//  R3 (192x72=13824): VT -> V2T -> CAT[tail]
//  CAT = 64x392 (25088) spans R2+R3 contiguously (26624 available).
//  Total 39424 ushorts = 78848 B -> 2 blocks/CU by LDS (157696 <= 163840).
//  VGPR must stay <= 128 for the 2nd block; compiler's natural choice for
//  this body is ~100 (R1 evidence) -> use relaxed bound (512,2), do NOT
//  force 4 (forcing 4 makes the compiler split 64 arch + 64 acc and spill).
#define LD_IN  200   // 192 + 8 pad
#define LD_K   200
#define LD_VT  72    // 64 + 8 pad
#define LD_P   72
#define LD_CAT 392   // 384 + 8 pad
#define LD_M   200
#define OFF_R1 0
#define OFF_R2 12800
#define OFF_R3 25600
#define SMEM_ELEMS 39424         // 78848 bytes
#define CATB OFF_R2

#define SCALE 0.17677669529663687f   // 32^-0.5
#define LOG2E 1.4426950408889634f

// ---------------- weight fp32 -> bf16 converter (runs every launch) ----------------
__global__ __launch_bounds__(256) void cvt_w(
    const float* __restrict__ a, const float* __restrict__ b, const float* __restrict__ c,
    const float* __restrict__ d, const float* __restrict__ e, unsigned short* __restrict__ o)
{
    int i = (blockIdx.x * 256 + threadIdx.x) * 4;
    if (i >= WB_ELEMS) return;
    const float* s; int off;
    if (i < O_KV)      { s = a; off = i - O_QKV; }
    else if (i < O_M1) { s = b; off = i - O_KV; }
    else if (i < O_M2) { s = c; off = i - O_M1; }
    else if (i < O_PW) { s = d; off = i - O_M2; }
    else               { s = e; off = i - O_PW; }
    float4 v = *(const float4*)(s + off);
    u16x4 r;
    r[0] = f2b(v.x); r[1] = f2b(v.y); r[2] = f2b(v.z); r[3] = f2b(v.w);
    *(u16x4*)(o + i) = r;
}

template<bool WB>
DEVINL s16x8 loadB(const unsigned short* wbp, const float* wfp, int off) {
    if constexpr (WB) {
        return *(const s16x8*)(wbp + off);
    } else {
        float4 v0 = *(const float4*)(wfp + off);
        float4 v1 = *(const float4*)(wfp + off + 4);
        s16x8 r;
        r[0] = (short)f2b(v0.x); r[1] = (short)f2b(v0.y); r[2] = (short)f2b(v0.z); r[3] = (short)f2b(v0.w);
        r[4] = (short)f2b(v1.x); r[5] = (short)f2b(v1.y); r[6] = (short)f2b(v1.z); r[7] = (short)f2b(v1.w);
        return r;
    }
}

template<bool WB>
__global__ __launch_bounds__(512, 2) void swin_fused(
    const float* __restrict__ x,
    const float* __restrict__ y,
    const float* __restrict__ mask_x,
    const float* __restrict__ mask_y,
    const float* __restrict__ qkv_w,
    const float* __restrict__ qkv_b,
    const float* __restrict__ kv_w,
    const float* __restrict__ kv_b,
    const float* __restrict__ rpb_x,
    const float* __restrict__ rpb_y,
    const float* __restrict__ m1w,
    const float* __restrict__ m1b,
    const float* __restrict__ m2w,
    const float* __restrict__ m2b,
    const float* __restrict__ pw,
    const float* __restrict__ pb,
    const int* __restrict__ rel_idx,
    const unsigned short* __restrict__ wb,   // bf16 weight cache (valid iff WB)
    float* __restrict__ out)
{
    __shared__ __align__(16) unsigned short smem[SMEM_ELEMS];

    const int tid  = threadIdx.x;
    const int w    = tid >> 6;          // wave 0..7
    const int lane = tid & 63;
    const int l16  = lane & 15;
    const int quad = lane >> 4;
    const int wm   = w >> 2;            // GEMM M-half (2 M-tiles each)
    const int wn   = w & 3;             // GEMM N-quarter
    const int rb   = w >> 1;            // attn row-block (16 rows)
    const int hh   = w & 1;             // attn head-half (3 heads)
    const int b    = blockIdx.x;        // window 0..2047
    const int widx = b & 1023;          // mask window index (b % nW)

    const unsigned short* wqkv = WB ? wb + O_QKV : nullptr;
    const unsigned short* wkv  = WB ? wb + O_KV  : nullptr;
    const unsigned short* wm1  = WB ? wb + O_M1  : nullptr;
    const unsigned short* wm2  = WB ? wb + O_M2  : nullptr;
    const unsigned short* wpw  = WB ? wb + O_PW  : nullptr;

    // ---------------- stage x -> R1 (fp32 -> bf16) ----------------
    {
        const float4* gx = (const float4*)(x + (size_t)b * 64 * 192);
        #pragma unroll
        for (int it = 0; it < 3; ++it) {
            int c = it * 512 + tid;                // 8-elem chunk, 24 per row
            int e = c * 8;
            int row = e / 192, col = e - row * 192;
            float4 v0 = gx[c * 2], v1 = gx[c * 2 + 1];
            u16x8 r;
            r[0] = f2b(v0.x); r[1] = f2b(v0.y); r[2] = f2b(v0.z); r[3] = f2b(v0.w);
            r[4] = f2b(v1.x); r[5] = f2b(v1.y); r[6] = f2b(v1.z); r[7] = f2b(v1.w);
            *(u16x8*)&smem[OFF_R1 + row * LD_IN + col] = r;
        }
    }
    __syncthreads();   // B1: x staged

    // ---------------- GEMM1: QKV = x @ qkv_w^T + b ----------------
    {
        s16x8 afr[2][6];
        #pragma unroll
        for (int mt = 0; mt < 2; ++mt)
            #pragma unroll
            for (int ks = 0; ks < 6; ++ks)
                afr[mt][ks] = *(const s16x8*)&smem[OFF_R1 + (wm * 32 + mt * 16 + l16) * LD_IN + ks * 32 + quad * 8];
        __syncthreads();   // B1b: all x-fragments in regs -> R1 reusable for Q

        #pragma unroll
        for (int nt = 0; nt < 9; ++nt) {
            int n0  = wn * 144 + nt * 16;
            int col = n0 + l16;
            f32x4 acc0 = {0,0,0,0}, acc1 = {0,0,0,0};
            #pragma unroll
            for (int ks = 0; ks < 6; ++ks) {
                s16x8 bf = loadB<WB>(wqkv, qkv_w, col * 192 + ks * 32 + quad * 8);
                acc0 = mfma16(afr[0][ks], bf, acc0);
                acc1 = mfma16(afr[1][ks], bf, acc1);
            }
            f32x4 accv[2] = {acc0, acc1};
            float bias = qkv_b[col];
            if (n0 < 192) {           // Q (scaled) -> R1 (over x)
                #pragma unroll
                for (int mt = 0; mt < 2; ++mt)
                    #pragma unroll
                    for (int r = 0; r < 4; ++r)
                        smem[OFF_R1 + (wm * 32 + mt * 16 + quad * 4 + r) * LD_K + col] =
                            f2b((accv[mt][r] + bias) * SCALE);
            } else if (n0 < 384) {    // K -> R2
                #pragma unroll
                for (int mt = 0; mt < 2; ++mt)
                    #pragma unroll
                    for (int r = 0; r < 4; ++r)
                        smem[OFF_R2 + (wm * 32 + mt * 16 + quad * 4 + r) * LD_K + (col - 192)] =
                            f2b(accv[mt][r] + bias);
            } else {                  // V -> transposed store V^T[d][tok] -> R3
                #pragma unroll
                for (int mt = 0; mt < 2; ++mt)
                    #pragma unroll
                    for (int r = 0; r < 4; ++r)
                        smem[OFF_R3 + (col - 384) * LD_VT + (wm * 32 + mt * 16 + quad * 4 + r)] =
                            f2b(accv[mt][r] + bias);
            }
        }
    }
    __syncthreads();   // B2: Q,K,VT visible

    // ---------------- hoist Q fragments to registers (shared by both attns) ----------------
    s16x8 aQ[3];
    #pragma unroll
    for (int hl = 0; hl < 3; ++hl)
        aQ[hl] = *(const s16x8*)&smem[OFF_R1 + (rb * 16 + l16) * LD_K + (hh * 3 + hl) * 32 + quad * 8];
    __syncthreads();   // B2b: Q in regs -> R1 reusable for P

    // ---------------- attention (shared for self/cross) ----------------
    // wave (rb, hh): 16 rows (rb*16..), 3 heads (hh*3..). Per-wave private P slot in R1.
    // idxv/maskv loaded inside (short live range); output packed to bf16 pairs (12 regs).
    auto do_attn = [&](const float* __restrict__ rpb,
                       const float* __restrict__ mask,
                       unsigned (&opk)[12]) {
        f32x4 oacc[3][2];
        #pragma unroll
        for (int hl = 0; hl < 3; ++hl) { f32x4 z = {0,0,0,0}; oacc[hl][0] = z; oacc[hl][1] = z; }
        int   idxv[16];
        float maskv[16];
        #pragma unroll
        for (int i = 0; i < 16; ++i) {
            int ntt = i >> 2, r = i & 3;
            int row = rb * 16 + quad * 4 + r;
            int col = ntt * 16 + l16;
            idxv[i]  = rel_idx[row * 64 + col];
            maskv[i] = mask[(size_t)widx * 4096 + row * 64 + col];
        }
        const int pbase = OFF_R1 + w * 16 * LD_P;
        #pragma unroll
        for (int hl = 0; hl < 3; ++hl) {
            int h = hh * 3 + hl;
            f32x4 sacc[4];
            #pragma unroll
            for (int ntt = 0; ntt < 4; ++ntt) {
                s16x8 bK = *(const s16x8*)&smem[OFF_R2 + (ntt * 16 + l16) * LD_K + h * 32 + quad * 8];
                f32x4 z = {0,0,0,0};
                sacc[ntt] = mfma16(aQ[hl], bK, z);
            }
            float sv[4][4];
            #pragma unroll
            for (int ntt = 0; ntt < 4; ++ntt)
                #pragma unroll
                for (int r = 0; r < 4; ++r)
                    sv[ntt][r] = sacc[ntt][r] + rpb[idxv[ntt * 4 + r] * 6 + h] + maskv[ntt * 4 + r];
            float pv[4][4];
            #pragma unroll
            for (int r = 0; r < 4; ++r) {
                float mx = fmaxf(fmaxf(sv[0][r], sv[1][r]), fmaxf(sv[2][r], sv[3][r]));
                mx = fmaxf(mx, __shfl_xor(mx, 1));
                mx = fmaxf(mx, __shfl_xor(mx, 2));
                mx = fmaxf(mx, __shfl_xor(mx, 4));
                mx = fmaxf(mx, __shfl_xor(mx, 8));
                float e0 = __builtin_amdgcn_exp2f((sv[0][r] - mx) * LOG2E);
                float e1 = __builtin_amdgcn_exp2f((sv[1][r] - mx) * LOG2E);
                float e2 = __builtin_amdgcn_exp2f((sv[2][r] - mx) * LOG2E);
                float e3 = __builtin_amdgcn_exp2f((sv[3][r] - mx) * LOG2E);
                float s = e0 + e1 + e2 + e3;
                s += __shfl_xor(s, 1);
                s += __shfl_xor(s, 2);
                s += __shfl_xor(s, 4);
                s += __shfl_xor(s, 8);
                float inv = __builtin_amdgcn_rcpf(s);
                pv[0][r] = e0 * inv; pv[1][r] = e1 * inv; pv[2][r] = e2 * inv; pv[3][r] = e3 * inv;
            }
            #pragma unroll
            for (int ntt = 0; ntt < 4; ++ntt)
                #pragma unroll
                for (int r = 0; r < 4; ++r)
                    smem[pbase + (quad * 4 + r) * LD_P + ntt * 16 + l16] = f2b(pv[ntt][r]);
            #pragma unroll
            for (int nd = 0; nd < 2; ++nd) {
                f32x4 o = oacc[hl][nd];
                #pragma unroll
                for (int kt = 0; kt < 2; ++kt) {
                    s16x8 aP = *(const s16x8*)&smem[pbase + l16 * LD_P + kt * 32 + quad * 8];
                    s16x8 bV = *(const s16x8*)&smem[OFF_R3 + (h * 32 + nd * 16 + l16) * LD_VT + kt * 32 + quad * 8];
                    o = mfma16(aP, bV, o);
                }
                oacc[hl][nd] = o;
            }
        }
        // pack O to bf16 pairs (lo = nd0, hi = nd1) -> 12 regs
        #pragma unroll
        for (int hl = 0; hl < 3; ++hl)
            #pragma unroll
            for (int r = 0; r < 4; ++r)
                opk[hl * 4 + r] = (unsigned)f2b(oacc[hl][0][r]) |
                                  ((unsigned)f2b(oacc[hl][1][r]) << 16);
    };

    unsigned opks[12];
    do_attn(rpb_x, mask_x, opks);
    __syncthreads();   // B3: attn1 done (P reads complete) -> R1 reusable for y

    // ---------------- stage y -> R1 ----------------
    {
        const float4* gy = (const float4*)(y + (size_t)b * 64 * 192);
        #pragma unroll
        for (int it = 0; it < 3; ++it) {
            int c = it * 512 + tid;
            int e = c * 8;
            int row = e / 192, col = e - row * 192;
            float4 v0 = gy[c * 2], v1 = gy[c * 2 + 1];
            u16x8 r;
            r[0] = f2b(v0.x); r[1] = f2b(v0.y); r[2] = f2b(v0.z); r[3] = f2b(v0.w);
            r[4] = f2b(v1.x); r[5] = f2b(v1.y); r[6] = f2b(v1.z); r[7] = f2b(v1.w);
            *(u16x8*)&smem[OFF_R1 + row * LD_IN + col] = r;
        }
    }
    __syncthreads();   // B3b: y staged

    // ---------------- GEMM1b: KV2 = y @ kv_w^T + b ----------------
    {
        s16x8 afr[2][6];
        #pragma unroll
        for (int mt = 0; mt < 2; ++mt)
            #pragma unroll
            for (int ks = 0; ks < 6; ++ks)
                afr[mt][ks] = *(const s16x8*)&smem[OFF_R1 + (wm * 32 + mt * 16 + l16) * LD_IN + ks * 32 + quad * 8];

        #pragma unroll
        for (int nt = 0; nt < 6; ++nt) {
            int n0  = wn * 96 + nt * 16;
            int col = n0 + l16;
            f32x4 acc0 = {0,0,0,0}, acc1 = {0,0,0,0};
            #pragma unroll
            for (int ks = 0; ks < 6; ++ks) {
                s16x8 bf = loadB<WB>(wkv, kv_w, col * 192 + ks * 32 + quad * 8);
                acc0 = mfma16(afr[0][ks], bf, acc0);
                acc1 = mfma16(afr[1][ks], bf, acc1);
            }
            f32x4 accv[2] = {acc0, acc1};
            float bias = kv_b[col];
            if (n0 < 192) {           // K2 overwrites K (R2)
                #pragma unroll
                for (int mt = 0; mt < 2; ++mt)
                    #pragma unroll
                    for (int r = 0; r < 4; ++r)
                        smem[OFF_R2 + (wm * 32 + mt * 16 + quad * 4 + r) * LD_K + col] =
                            f2b(accv[mt][r] + bias);
            } else {                  // V2 -> V2^T overwrites VT (R3)
                #pragma unroll
                for (int mt = 0; mt < 2; ++mt)
                    #pragma unroll
                    for (int r = 0; r < 4; ++r)
                        smem[OFF_R3 + (col - 192) * LD_VT + (wm * 32 + mt * 16 + quad * 4 + r)] =
                            f2b(accv[mt][r] + bias);
            }
        }
    }
    __syncthreads();   // B4: K2,V2T visible; all y-fragment reads done -> R1 reusable for P

    unsigned opkc[12];
    do_attn(rpb_y, mask_y, opkc);
    __syncthreads();   // B5: attn2 done -> K2(R2)/V2T(R3) dead -> CAT may be written

    // ---------------- CAT = [x_self | x_cross] (64x392 over R2+R3) ----------------
    #pragma unroll
    for (int hl = 0; hl < 3; ++hl) {
        int h = hh * 3 + hl;
        #pragma unroll
        for (int r = 0; r < 4; ++r) {
            int row = rb * 16 + quad * 4 + r;
            unsigned ps = opks[hl * 4 + r];
            unsigned pc = opkc[hl * 4 + r];
            smem[CATB + row * LD_CAT + h * 32 + l16]             = (unsigned short)(ps & 0xFFFFu);
            smem[CATB + row * LD_CAT + h * 32 + 16 + l16]        = (unsigned short)(ps >> 16);
            smem[CATB + row * LD_CAT + 192 + h * 32 + l16]       = (unsigned short)(pc & 0xFFFFu);
            smem[CATB + row * LD_CAT + 192 + h * 32 + 16 + l16]  = (unsigned short)(pc >> 16);
        }
    }
    __syncthreads();   // B6

    // ---------------- merge1 + leaky_relu -> M1 (R1) ----------------
    // ks-outer, acc[3 nt][2 mt] live (24 regs), A-fragments transient (8 regs)
    {
        f32x4 acc[3][2];
        #pragma unroll
        for (int nt = 0; nt < 3; ++nt) { f32x4 z = {0,0,0,0}; acc[nt][0] = z; acc[nt][1] = z; }
        #pragma unroll
        for (int ks = 0; ks < 12; ++ks) {
            s16x8 c0 = *(const s16x8*)&smem[CATB + (wm * 32 + l16) * LD_CAT + ks * 32 + quad * 8];
            s16x8 c1 = *(const s16x8*)&smem[CATB + (wm * 32 + 16 + l16) * LD_CAT + ks * 32 + quad * 8];
            #pragma unroll
            for (int nt = 0; nt < 3; ++nt) {
                int col = wn * 48 + nt * 16 + l16;
                s16x8 bf = loadB<WB>(wm1, m1w, col * 384 + ks * 32 + quad * 8);
                acc[nt][0] = mfma16(c0, bf, acc[nt][0]);
                acc[nt][1] = mfma16(c1, bf, acc[nt][1]);
            }
        }
        #pragma unroll
        for (int nt = 0; nt < 3; ++nt) {
            int col = wn * 48 + nt * 16 + l16;
            float bias = m1b[col];
            #pragma unroll
            for (int mt = 0; mt < 2; ++mt)
                #pragma unroll
                for (int r = 0; r < 4; ++r) {
                    float v = acc[nt][mt][r] + bias;
                    v = (v > 0.f) ? v : 0.2f * v;
                    smem[OFF_R1 + (wm * 32 + mt * 16 + quad * 4 + r) * LD_M + col] = f2b(v);
                }
        }
    }
    __syncthreads();   // B7

    // ---------------- merge2 -> M2 (R2; CAT dead) ----------------
    {
        s16x8 afr[2][6];
        #pragma unroll
        for (int mt = 0; mt < 2; ++mt)
            #pragma unroll
            for (int ks = 0; ks < 6; ++ks)
                afr[mt][ks] = *(const s16x8*)&smem[OFF_R1 + (wm * 32 + mt * 16 + l16) * LD_M + ks * 32 + quad * 8];

        #pragma unroll
        for (int nt = 0; nt < 3; ++nt) {
            int n0  = wn * 48 + nt * 16;
            int col = n0 + l16;
            f32x4 acc0 = {0,0,0,0}, acc1 = {0,0,0,0};
            #pragma unroll
            for (int ks = 0; ks < 6; ++ks) {
                s16x8 bf = loadB<WB>(wm2, m2w, col * 192 + ks * 32 + quad * 8);
                acc0 = mfma16(afr[0][ks], bf, acc0);
                acc1 = mfma16(afr[1][ks], bf, acc1);
            }
            f32x4 accv[2] = {acc0, acc1};
            float bias = m2b[col];
            #pragma unroll
            for (int mt = 0; mt < 2; ++mt)
                #pragma unroll
                for (int r = 0; r < 4; ++r)
                    smem[OFF_R2 + (wm * 32 + mt * 16 + quad * 4 + r) * LD_M + col] = f2b(accv[mt][r] + bias);
        }
    }
    __syncthreads();   // B8

    // ---------------- proj -> out (fp32) ----------------
    {
        s16x8 afr[2][6];
        #pragma unroll
        for (int mt = 0; mt < 2; ++mt)
            #pragma unroll
            for (int ks = 0; ks < 6; ++ks)
                afr[mt][ks] = *(const s16x8*)&smem[OFF_R2 + (wm * 32 + mt * 16 + l16) * LD_M + ks * 32 + quad * 8];

        #pragma unroll
        for (int nt = 0; nt < 3; ++nt) {
            int n0  = wn * 48 + nt * 16;
            int col = n0 + l16;
            f32x4 acc0 = {0,0,0,0}, acc1 = {0,0,0,0};
            #pragma unroll
            for (int ks = 0; ks < 6; ++ks) {
                s16x8 bf = loadB<WB>(wpw, pw, col * 192 + ks * 32 + quad * 8);
                acc0 = mfma16(afr[0][ks], bf, acc0);
                acc1 = mfma16(afr[1][ks], bf, acc1);
            }
            f32x4 accv[2] = {acc0, acc1};
            float bias = pb[col];
            #pragma unroll
            for (int mt = 0; mt < 2; ++mt)
                #pragma unroll
                for (int r = 0; r < 4; ++r) {
                    int row = wm * 32 + mt * 16 + quad * 4 + r;
                    out[((size_t)b * 64 + row) * 192 + col] = accv[mt][r] + bias;
                }
        }
    }
}

extern "C" void kernel_launch(void* const* d_in, const int* in_sizes, int n_in,
                              void* d_out, int out_size, void* d_ws, size_t ws_size,
                              hipStream_t stream) {
    (void)in_sizes; (void)n_in; (void)out_size;
    const float* x    = (const float*)d_in[0];
    const float* y    = (const float*)d_in[1];
    const float* mx   = (const float*)d_in[2];
    const float* my   = (const float*)d_in[3];
    const float* qw   = (const float*)d_in[4];
    const float* qb   = (const float*)d_in[5];
    const float* kw   = (const float*)d_in[6];
    const float* kb   = (const float*)d_in[7];
    const float* rx   = (const float*)d_in[8];
    const float* ry   = (const float*)d_in[9];
    const float* m1w  = (const float*)d_in[10];
    const float* m1b  = (const float*)d_in[11];
    const float* m2w  = (const float*)d_in[12];
    const float* m2b  = (const float*)d_in[13];
    const float* pw   = (const float*)d_in[14];
    const float* pb   = (const float*)d_in[15];
    const int*   ridx = (const int*)d_in[16];
    float* out = (float*)d_out;

    if (ws_size >= (size_t)WB_BYTES) {
        unsigned short* wbuf = (unsigned short*)d_ws;
        cvt_w<<<WB_ELEMS / 4 / 256, 256, 0, stream>>>(qw, kw, m1w, m2w, pw, wbuf);
        swin_fused<true><<<2048, 512, 0, stream>>>(
            x, y, mx, my, qw, qb, kw, kb, rx, ry, m1w, m1b, m2w, m2b, pw, pb, ridx,
            wbuf, out);
    } else {
        swin_fused<false><<<2048, 512, 0, stream>>>(
            x, y, mx, my, qw, qb, kw, kb, rx, ry, m1w, m1b, m2w, m2b, pw, pb, ridx,
            nullptr, out);
    }
}

// Round 5
// 652.259 us; speedup vs baseline: 1.0010x; 1.0010x over previous
//
#include <hip/hip_runtime.h>

#define DEVINL __device__ __forceinline__

typedef __attribute__((ext_vector_type(8))) short          s16x8;
typedef __attribute__((ext_vector_type(8))) unsigned short u16x8;
typedef __attribute__((ext_vector_type(4))) unsigned short u16x4;
typedef __attribute__((ext_vector_type(4))) float          f32x4;

DEVINL unsigned short f2b(float f) {
    union { float f; unsigned int u; } c; c.f = f;
    return (unsigned short)((c.u + 0x7FFFu + ((c.u >> 16) & 1u)) >> 16);
}
DEVINL f32x4 mfma16(s16x8 a, s16x8 b, f32x4 c) {
    return __builtin_amdgcn_mfma_f32_16x16x32_bf16(a, b, c, 0, 0, 0);
}

// ---- bf16 weight cache in d_ws (concatenated, row-major as in HBM) ----
#define QKV_ELEMS 110592
#define KV_ELEMS  73728
#define M1_ELEMS  73728
#define M2_ELEMS  36864
#define PW_ELEMS  36864
#define O_QKV 0
#define O_KV  110592
#define O_M1  184320
#define O_M2  258048
#define O_PW  294912
#define WB_ELEMS 331776
#define WB_BYTES (WB_ELEMS * 2)

// ---- LDS layout (ushort elements). Region lifetimes:
//  R1 (64x200=12800): x -> Q -> P(attn1) -> y -> P(attn2) -> M1
//  R2 (64x200=12800): K -> K2 -> CAT[cols 0..)   -> M2
//  R3 (192x72=13824): VT -> V2T -> CAT[tail]
//  CAT = 64x392 (25088) spans R2+R3 contiguously (26624 available).
//  Total 39424 ushorts = 78848 B -> 2 blocks/CU by LDS (157696 <= 163840).
//  2nd block also needs TOTAL (arch+acc) regs <= 128/wave -> register diet
//  in attn (inline mask, packed idx, per-head O release) + forced (512,4).
#define LD_IN  200   // 192 + 8 pad
#define LD_K   200
#define LD_VT  72    // 64 + 8 pad
#define LD_P   72
#define LD_CAT 392   // 384 + 8 pad
#define LD_M   200
#define OFF_R1 0
#define OFF_R2 12800
#define OFF_R3 25600
#define SMEM_ELEMS 39424         // 78848 bytes
#define CATB OFF_R2

#define SCALE 0.17677669529663687f   // 32^-0.5
#define LOG2E 1.4426950408889634f

// ---------------- weight fp32 -> bf16 converter (runs every launch) ----------------
__global__ __launch_bounds__(256) void cvt_w(
    const float* __restrict__ a, const float* __restrict__ b, const float* __restrict__ c,
    const float* __restrict__ d, const float* __restrict__ e, unsigned short* __restrict__ o)
{
    int i = (blockIdx.x * 256 + threadIdx.x) * 4;
    if (i >= WB_ELEMS) return;
    const float* s; int off;
    if (i < O_KV)      { s = a; off = i - O_QKV; }
    else if (i < O_M1) { s = b; off = i - O_KV; }
    else if (i < O_M2) { s = c; off = i - O_M1; }
    else if (i < O_PW) { s = d; off = i - O_M2; }
    else               { s = e; off = i - O_PW; }
    float4 v = *(const float4*)(s + off);
    u16x4 r;
    r[0] = f2b(v.x); r[1] = f2b(v.y); r[2] = f2b(v.z); r[3] = f2b(v.w);
    *(u16x4*)(o + i) = r;
}

template<bool WB>
DEVINL s16x8 loadB(const unsigned short* wbp, const float* wfp, int off) {
    if constexpr (WB) {
        return *(const s16x8*)(wbp + off);
    } else {
        float4 v0 = *(const float4*)(wfp + off);
        float4 v1 = *(const float4*)(wfp + off + 4);
        s16x8 r;
        r[0] = (short)f2b(v0.x); r[1] = (short)f2b(v0.y); r[2] = (short)f2b(v0.z); r[3] = (short)f2b(v0.w);
        r[4] = (short)f2b(v1.x); r[5] = (short)f2b(v1.y); r[6] = (short)f2b(v1.z); r[7] = (short)f2b(v1.w);
        return r;
    }
}

template<bool WB>
__global__ __launch_bounds__(512, 4) void swin_fused(
    const float* __restrict__ x,
    const float* __restrict__ y,
    const float* __restrict__ mask_x,
    const float* __restrict__ mask_y,
    const float* __restrict__ qkv_w,
    const float* __restrict__ qkv_b,
    const float* __restrict__ kv_w,
    const float* __restrict__ kv_b,
    const float* __restrict__ rpb_x,
    const float* __restrict__ rpb_y,
    const float* __restrict__ m1w,
    const float* __restrict__ m1b,
    const float* __restrict__ m2w,
    const float* __restrict__ m2b,
    const float* __restrict__ pw,
    const float* __restrict__ pb,
    const int* __restrict__ rel_idx,
    const unsigned short* __restrict__ wb,   // bf16 weight cache (valid iff WB)
    float* __restrict__ out)
{
    __shared__ __align__(16) unsigned short smem[SMEM_ELEMS];

    const int tid  = threadIdx.x;
    const int w    = tid >> 6;          // wave 0..7
    const int lane = tid & 63;
    const int l16  = lane & 15;
    const int quad = lane >> 4;
    const int wm   = w >> 2;            // GEMM M-half (2 M-tiles each)
    const int wn   = w & 3;             // GEMM N-quarter
    const int rb   = w >> 1;            // attn row-block (16 rows)
    const int hh   = w & 1;             // attn head-half (3 heads)
    const int b    = blockIdx.x;        // window 0..2047
    const int widx = b & 1023;          // mask window index (b % nW)

    const unsigned short* wqkv = WB ? wb + O_QKV : nullptr;
    const unsigned short* wkv  = WB ? wb + O_KV  : nullptr;
    const unsigned short* wm1  = WB ? wb + O_M1  : nullptr;
    const unsigned short* wm2  = WB ? wb + O_M2  : nullptr;
    const unsigned short* wpw  = WB ? wb + O_PW  : nullptr;

    // ---------------- stage x -> R1 (fp32 -> bf16) ----------------
    {
        const float4* gx = (const float4*)(x + (size_t)b * 64 * 192);
        #pragma unroll
        for (int it = 0; it < 3; ++it) {
            int c = it * 512 + tid;                // 8-elem chunk, 24 per row
            int e = c * 8;
            int row = e / 192, col = e - row * 192;
            float4 v0 = gx[c * 2], v1 = gx[c * 2 + 1];
            u16x8 r;
            r[0] = f2b(v0.x); r[1] = f2b(v0.y); r[2] = f2b(v0.z); r[3] = f2b(v0.w);
            r[4] = f2b(v1.x); r[5] = f2b(v1.y); r[6] = f2b(v1.z); r[7] = f2b(v1.w);
            *(u16x8*)&smem[OFF_R1 + row * LD_IN + col] = r;
        }
    }
    __syncthreads();   // B1: x staged

    // ---------------- GEMM1: QKV = x @ qkv_w^T + b ----------------
    {
        s16x8 afr[2][6];
        #pragma unroll
        for (int mt = 0; mt < 2; ++mt)
            #pragma unroll
            for (int ks = 0; ks < 6; ++ks)
                afr[mt][ks] = *(const s16x8*)&smem[OFF_R1 + (wm * 32 + mt * 16 + l16) * LD_IN + ks * 32 + quad * 8];
        __syncthreads();   // B1b: all x-fragments in regs -> R1 reusable for Q

        #pragma unroll
        for (int nt = 0; nt < 9; ++nt) {
            int n0  = wn * 144 + nt * 16;
            int col = n0 + l16;
            f32x4 acc0 = {0,0,0,0}, acc1 = {0,0,0,0};
            #pragma unroll
            for (int ks = 0; ks < 6; ++ks) {
                s16x8 bf = loadB<WB>(wqkv, qkv_w, col * 192 + ks * 32 + quad * 8);
                acc0 = mfma16(afr[0][ks], bf, acc0);
                acc1 = mfma16(afr[1][ks], bf, acc1);
            }
            f32x4 accv[2] = {acc0, acc1};
            float bias = qkv_b[col];
            if (n0 < 192) {           // Q (scaled) -> R1 (over x)
                #pragma unroll
                for (int mt = 0; mt < 2; ++mt)
                    #pragma unroll
                    for (int r = 0; r < 4; ++r)
                        smem[OFF_R1 + (wm * 32 + mt * 16 + quad * 4 + r) * LD_K + col] =
                            f2b((accv[mt][r] + bias) * SCALE);
            } else if (n0 < 384) {    // K -> R2
                #pragma unroll
                for (int mt = 0; mt < 2; ++mt)
                    #pragma unroll
                    for (int r = 0; r < 4; ++r)
                        smem[OFF_R2 + (wm * 32 + mt * 16 + quad * 4 + r) * LD_K + (col - 192)] =
                            f2b(accv[mt][r] + bias);
            } else {                  // V -> transposed store V^T[d][tok] -> R3
                #pragma unroll
                for (int mt = 0; mt < 2; ++mt)
                    #pragma unroll
                    for (int r = 0; r < 4; ++r)
                        smem[OFF_R3 + (col - 384) * LD_VT + (wm * 32 + mt * 16 + quad * 4 + r)] =
                            f2b(accv[mt][r] + bias);
            }
        }
    }
    __syncthreads();   // B2: Q,K,VT visible

    // ---------------- hoist Q fragments to registers (shared by both attns) ----------------
    s16x8 aQ[3];
    #pragma unroll
    for (int hl = 0; hl < 3; ++hl)
        aQ[hl] = *(const s16x8*)&smem[OFF_R1 + (rb * 16 + l16) * LD_K + (hh * 3 + hl) * 32 + quad * 8];
    __syncthreads();   // B2b: Q in regs -> R1 reusable for P

    // ---------------- attention (shared for self/cross) ----------------
    // wave (rb, hh): 16 rows (rb*16..), 3 heads (hh*3..). Per-wave private P slot in R1.
    // Register diet: mask loaded inline (no maskv[16]); rel-idx packed 2x16b (8 regs);
    // O released per head into packed bf16 (opk, 12 regs).
    auto do_attn = [&](const float* __restrict__ rpb,
                       const float* __restrict__ mask,
                       unsigned (&opk)[12]) {
        // idxp[ntt*2 + (r>>1)] : lo = rel_idx(row+r_even)*6, hi = rel_idx(row+r_odd)*6
        unsigned idxp[8];
        #pragma unroll
        for (int p = 0; p < 8; ++p) {
            int ntt = p >> 1, r0 = (p & 1) * 2;
            int row = rb * 16 + quad * 4;
            int col = ntt * 16 + l16;
            unsigned lo = (unsigned)rel_idx[(row + r0)     * 64 + col] * 6u;
            unsigned hi = (unsigned)rel_idx[(row + r0 + 1) * 64 + col] * 6u;
            idxp[p] = lo | (hi << 16);
        }
        const float* mrow = mask + (size_t)widx * 4096 + (rb * 16 + quad * 4) * 64 + l16;
        const int pbase = OFF_R1 + w * 16 * LD_P;
        #pragma unroll
        for (int hl = 0; hl < 3; ++hl) {
            int h = hh * 3 + hl;
            f32x4 sacc[4];
            #pragma unroll
            for (int ntt = 0; ntt < 4; ++ntt) {
                s16x8 bK = *(const s16x8*)&smem[OFF_R2 + (ntt * 16 + l16) * LD_K + h * 32 + quad * 8];
                f32x4 z = {0,0,0,0};
                sacc[ntt] = mfma16(aQ[hl], bK, z);
            }
            float sv[4][4];
            #pragma unroll
            for (int ntt = 0; ntt < 4; ++ntt)
                #pragma unroll
                for (int r = 0; r < 4; ++r) {
                    unsigned idx6 = (idxp[ntt * 2 + (r >> 1)] >> ((r & 1) * 16)) & 0xFFFFu;
                    sv[ntt][r] = sacc[ntt][r] + rpb[idx6 + h] + mrow[r * 64 + ntt * 16];
                }
            float pv[4][4];
            #pragma unroll
            for (int r = 0; r < 4; ++r) {
                float mx = fmaxf(fmaxf(sv[0][r], sv[1][r]), fmaxf(sv[2][r], sv[3][r]));
                mx = fmaxf(mx, __shfl_xor(mx, 1));
                mx = fmaxf(mx, __shfl_xor(mx, 2));
                mx = fmaxf(mx, __shfl_xor(mx, 4));
                mx = fmaxf(mx, __shfl_xor(mx, 8));
                float e0 = __builtin_amdgcn_exp2f((sv[0][r] - mx) * LOG2E);
                float e1 = __builtin_amdgcn_exp2f((sv[1][r] - mx) * LOG2E);
                float e2 = __builtin_amdgcn_exp2f((sv[2][r] - mx) * LOG2E);
                float e3 = __builtin_amdgcn_exp2f((sv[3][r] - mx) * LOG2E);
                float s = e0 + e1 + e2 + e3;
                s += __shfl_xor(s, 1);
                s += __shfl_xor(s, 2);
                s += __shfl_xor(s, 4);
                s += __shfl_xor(s, 8);
                float inv = __builtin_amdgcn_rcpf(s);
                pv[0][r] = e0 * inv; pv[1][r] = e1 * inv; pv[2][r] = e2 * inv; pv[3][r] = e3 * inv;
            }
            #pragma unroll
            for (int ntt = 0; ntt < 4; ++ntt)
                #pragma unroll
                for (int r = 0; r < 4; ++r)
                    smem[pbase + (quad * 4 + r) * LD_P + ntt * 16 + l16] = f2b(pv[ntt][r]);
            // PV: per-head accumulators, released into packed bf16 immediately
            f32x4 oh0 = {0,0,0,0}, oh1 = {0,0,0,0};
            #pragma unroll
            for (int kt = 0; kt < 2; ++kt) {
                s16x8 aP  = *(const s16x8*)&smem[pbase + l16 * LD_P + kt * 32 + quad * 8];
                s16x8 bV0 = *(const s16x8*)&smem[OFF_R3 + (h * 32 + l16) * LD_VT + kt * 32 + quad * 8];
                s16x8 bV1 = *(const s16x8*)&smem[OFF_R3 + (h * 32 + 16 + l16) * LD_VT + kt * 32 + quad * 8];
                oh0 = mfma16(aP, bV0, oh0);
                oh1 = mfma16(aP, bV1, oh1);
            }
            #pragma unroll
            for (int r = 0; r < 4; ++r)
                opk[hl * 4 + r] = (unsigned)f2b(oh0[r]) | ((unsigned)f2b(oh1[r]) << 16);
        }
    };

    unsigned opks[12];
    do_attn(rpb_x, mask_x, opks);
    __syncthreads();   // B3: attn1 done (P reads complete) -> R1 reusable for y

    // ---------------- stage y -> R1 ----------------
    {
        const float4* gy = (const float4*)(y + (size_t)b * 64 * 192);
        #pragma unroll
        for (int it = 0; it < 3; ++it) {
            int c = it * 512 + tid;
            int e = c * 8;
            int row = e / 192, col = e - row * 192;
            float4 v0 = gy[c * 2], v1 = gy[c * 2 + 1];
            u16x8 r;
            r[0] = f2b(v0.x); r[1] = f2b(v0.y); r[2] = f2b(v0.z); r[3] = f2b(v0.w);
            r[4] = f2b(v1.x); r[5] = f2b(v1.y); r[6] = f2b(v1.z); r[7] = f2b(v1.w);
            *(u16x8*)&smem[OFF_R1 + row * LD_IN + col] = r;
        }
    }
    __syncthreads();   // B3b: y staged

    // ---------------- GEMM1b: KV2 = y @ kv_w^T + b ----------------
    {
        s16x8 afr[2][6];
        #pragma unroll
        for (int mt = 0; mt < 2; ++mt)
            #pragma unroll
            for (int ks = 0; ks < 6; ++ks)
                afr[mt][ks] = *(const s16x8*)&smem[OFF_R1 + (wm * 32 + mt * 16 + l16) * LD_IN + ks * 32 + quad * 8];

        #pragma unroll
        for (int nt = 0; nt < 6; ++nt) {
            int n0  = wn * 96 + nt * 16;
            int col = n0 + l16;
            f32x4 acc0 = {0,0,0,0}, acc1 = {0,0,0,0};
            #pragma unroll
            for (int ks = 0; ks < 6; ++ks) {
                s16x8 bf = loadB<WB>(wkv, kv_w, col * 192 + ks * 32 + quad * 8);
                acc0 = mfma16(afr[0][ks], bf, acc0);
                acc1 = mfma16(afr[1][ks], bf, acc1);
            }
            f32x4 accv[2] = {acc0, acc1};
            float bias = kv_b[col];
            if (n0 < 192) {           // K2 overwrites K (R2)
                #pragma unroll
                for (int mt = 0; mt < 2; ++mt)
                    #pragma unroll
                    for (int r = 0; r < 4; ++r)
                        smem[OFF_R2 + (wm * 32 + mt * 16 + quad * 4 + r) * LD_K + col] =
                            f2b(accv[mt][r] + bias);
            } else {                  // V2 -> V2^T overwrites VT (R3)
                #pragma unroll
                for (int mt = 0; mt < 2; ++mt)
                    #pragma unroll
                    for (int r = 0; r < 4; ++r)
                        smem[OFF_R3 + (col - 192) * LD_VT + (wm * 32 + mt * 16 + quad * 4 + r)] =
                            f2b(accv[mt][r] + bias);
            }
        }
    }
    __syncthreads();   // B4: K2,V2T visible; all y-fragment reads done -> R1 reusable for P

    unsigned opkc[12];
    do_attn(rpb_y, mask_y, opkc);
    __syncthreads();   // B5: attn2 done -> K2(R2)/V2T(R3) dead -> CAT may be written

    // ---------------- CAT = [x_self | x_cross] (64x392 over R2+R3) ----------------
    #pragma unroll
    for (int hl = 0; hl < 3; ++hl) {
        int h = hh * 3 + hl;
        #pragma unroll
        for (int r = 0; r < 4; ++r) {
            int row = rb * 16 + quad * 4 + r;
            unsigned ps = opks[hl * 4 + r];
            unsigned pc = opkc[hl * 4 + r];
            smem[CATB + row * LD_CAT + h * 32 + l16]             = (unsigned short)(ps & 0xFFFFu);
            smem[CATB + row * LD_CAT + h * 32 + 16 + l16]        = (unsigned short)(ps >> 16);
            smem[CATB + row * LD_CAT + 192 + h * 32 + l16]       = (unsigned short)(pc & 0xFFFFu);
            smem[CATB + row * LD_CAT + 192 + h * 32 + 16 + l16]  = (unsigned short)(pc >> 16);
        }
    }
    __syncthreads();   // B6

    // ---------------- merge1 + leaky_relu -> M1 (R1) ----------------
    // ks-outer, acc[3 nt][2 mt] live (24 regs), A-fragments transient (8 regs)
    {
        f32x4 acc[3][2];
        #pragma unroll
        for (int nt = 0; nt < 3; ++nt) { f32x4 z = {0,0,0,0}; acc[nt][0] = z; acc[nt][1] = z; }
        #pragma unroll
        for (int ks = 0; ks < 12; ++ks) {
            s16x8 c0 = *(const s16x8*)&smem[CATB + (wm * 32 + l16) * LD_CAT + ks * 32 + quad * 8];
            s16x8 c1 = *(const s16x8*)&smem[CATB + (wm * 32 + 16 + l16) * LD_CAT + ks * 32 + quad * 8];
            #pragma unroll
            for (int nt = 0; nt < 3; ++nt) {
                int col = wn * 48 + nt * 16 + l16;
                s16x8 bf = loadB<WB>(wm1, m1w, col * 384 + ks * 32 + quad * 8);
                acc[nt][0] = mfma16(c0, bf, acc[nt][0]);
                acc[nt][1] = mfma16(c1, bf, acc[nt][1]);
            }
        }
        #pragma unroll
        for (int nt = 0; nt < 3; ++nt) {
            int col = wn * 48 + nt * 16 + l16;
            float bias = m1b[col];
            #pragma unroll
            for (int mt = 0; mt < 2; ++mt)
                #pragma unroll
                for (int r = 0; r < 4; ++r) {
                    float v = acc[nt][mt][r] + bias;
                    v = (v > 0.f) ? v : 0.2f * v;
                    smem[OFF_R1 + (wm * 32 + mt * 16 + quad * 4 + r) * LD_M + col] = f2b(v);
                }
        }
    }
    __syncthreads();   // B7

    // ---------------- merge2 -> M2 (R2; CAT dead) ----------------
    {
        s16x8 afr[2][6];
        #pragma unroll
        for (int mt = 0; mt < 2; ++mt)
            #pragma unroll
            for (int ks = 0; ks < 6; ++ks)
                afr[mt][ks] = *(const s16x8*)&smem[OFF_R1 + (wm * 32 + mt * 16 + l16) * LD_M + ks * 32 + quad * 8];

        #pragma unroll
        for (int nt = 0; nt < 3; ++nt) {
            int n0  = wn * 48 + nt * 16;
            int col = n0 + l16;
            f32x4 acc0 = {0,0,0,0}, acc1 = {0,0,0,0};
            #pragma unroll
            for (int ks = 0; ks < 6; ++ks) {
                s16x8 bf = loadB<WB>(wm2, m2w, col * 192 + ks * 32 + quad * 8);
                acc0 = mfma16(afr[0][ks], bf, acc0);
                acc1 = mfma16(afr[1][ks], bf, acc1);
            }
            f32x4 accv[2] = {acc0, acc1};
            float bias = m2b[col];
            #pragma unroll
            for (int mt = 0; mt < 2; ++mt)
                #pragma unroll
                for (int r = 0; r < 4; ++r)
                    smem[OFF_R2 + (wm * 32 + mt * 16 + quad * 4 + r) * LD_M + col] = f2b(accv[mt][r] + bias);
        }
    }
    __syncthreads();   // B8

    // ---------------- proj -> out (fp32) ----------------
    {
        s16x8 afr[2][6];
        #pragma unroll
        for (int mt = 0; mt < 2; ++mt)
            #pragma unroll
            for (int ks = 0; ks < 6; ++ks)
                afr[mt][ks] = *(const s16x8*)&smem[OFF_R2 + (wm * 32 + mt * 16 + l16) * LD_M + ks * 32 + quad * 8];

        #pragma unroll
        for (int nt = 0; nt < 3; ++nt) {
            int n0  = wn * 48 + nt * 16;
            int col = n0 + l16;
            f32x4 acc0 = {0,0,0,0}, acc1 = {0,0,0,0};
            #pragma unroll
            for (int ks = 0; ks < 6; ++ks) {
                s16x8 bf = loadB<WB>(wpw, pw, col * 192 + ks * 32 + quad * 8);
                acc0 = mfma16(afr[0][ks], bf, acc0);
                acc1 = mfma16(afr[1][ks], bf, acc1);
            }
            f32x4 accv[2] = {acc0, acc1};
            float bias = pb[col];
            #pragma unroll
            for (int mt = 0; mt < 2; ++mt)
                #pragma unroll
                for (int r = 0; r < 4; ++r) {
                    int row = wm * 32 + mt * 16 + quad * 4 + r;
                    out[((size_t)b * 64 + row) * 192 + col] = accv[mt][r] + bias;
                }
        }
    }
}

extern "C" void kernel_launch(void* const* d_in, const int* in_sizes, int n_in,
                              void* d_out, int out_size, void* d_ws, size_t ws_size,
                              hipStream_t stream) {
    (void)in_sizes; (void)n_in; (void)out_size;
    const float* x    = (const float*)d_in[0];
    const float* y    = (const float*)d_in[1];
    const float* mx   = (const float*)d_in[2];
    const float* my   = (const float*)d_in[3];
    const float* qw   = (const float*)d_in[4];
    const float* qb   = (const float*)d_in[5];
    const float* kw   = (const float*)d_in[6];
    const float* kb   = (const float*)d_in[7];
    const float* rx   = (const float*)d_in[8];
    const float* ry   = (const float*)d_in[9];
    const float* m1w  = (const float*)d_in[10];
    const float* m1b  = (const float*)d_in[11];
    const float* m2w  = (const float*)d_in[12];
    const float* m2b  = (const float*)d_in[13];
    const float* pw   = (const float*)d_in[14];
    const float* pb   = (const float*)d_in[15];
    const int*   ridx = (const int*)d_in[16];
    float* out = (float*)d_out;

    if (ws_size >= (size_t)WB_BYTES) {
        unsigned short* wbuf = (unsigned short*)d_ws;
        cvt_w<<<WB_ELEMS / 4 / 256, 256, 0, stream>>>(qw, kw, m1w, m2w, pw, wbuf);
        swin_fused<true><<<2048, 512, 0, stream>>>(
            x, y, mx, my, qw, qb, kw, kb, rx, ry, m1w, m1b, m2w, m2b, pw, pb, ridx,
            wbuf, out);
    } else {
        swin_fused<false><<<2048, 512, 0, stream>>>(
            x, y, mx, my, qw, qb, kw, kb, rx, ry, m1w, m1b, m2w, m2b, pw, pb, ridx,
            nullptr, out);
    }
}

// Round 7
// 523.946 us; speedup vs baseline: 1.2461x; 1.2449x over previous
//
#include <hip/hip_runtime.h>

#define DEVINL __device__ __forceinline__

typedef __attribute__((ext_vector_type(8))) short          s16x8;
typedef __attribute__((ext_vector_type(8))) unsigned short u16x8;
typedef __attribute__((ext_vector_type(4))) unsigned short u16x4;
typedef __attribute__((ext_vector_type(4))) float          f32x4;

DEVINL unsigned short f2b(float f) {
    union { float f; unsigned int u; } c; c.f = f;
    return (unsigned short)((c.u + 0x7FFFu + ((c.u >> 16) & 1u)) >> 16);
}
DEVINL f32x4 mfma16(s16x8 a, s16x8 b, f32x4 c) {
    return __builtin_amdgcn_mfma_f32_16x16x32_bf16(a, b, c, 0, 0, 0);
}

// ---- bf16 weight cache in d_ws (concatenated, row-major as in HBM) ----
#define QKV_ELEMS 110592
#define KV_ELEMS  73728
#define M1_ELEMS  73728
#define M2_ELEMS  36864
#define PW_ELEMS  36864
#define O_QKV 0
#define O_KV  110592
#define O_M1  184320
#define O_M2  258048
#define O_PW  294912
#define WB_ELEMS 331776
#define WB_BYTES (WB_ELEMS * 2)

// ---- R6: one block = 2 windows (M=128). Weight-load latency amortized 2x.
// LDS regions (ushort elems):
//  R1 (128x200=25600): x2 -> Q2 -> P -> y2 -> P -> M1
//  R2 (128x200=25600): K2win -> K2'2win -> CAT[0..) -> M2
//  R3 (2x192x72=27648): VT2win -> V2T2win -> CAT[tail]
//  CAT = 128x392 = 50176 spans R2+R3 (53248 avail).
//  Total 78848 ushorts = 157696 B -> 1 block/CU (<=163840), 8 waves.
#define LD_IN  200   // 192 + 8 pad
#define LD_K   200
#define LD_VT  72    // 64 + 8 pad
#define LD_P   72
#define LD_CAT 392   // 384 + 8 pad
#define LD_M   200
#define OFF_R1 0
#define OFF_R2 25600
#define OFF_R3 51200
#define VT_WIN 13824             // 192*72 per window
#define SMEM_ELEMS 78848         // 157696 bytes
#define CATB OFF_R2

#define SCALE 0.17677669529663687f   // 32^-0.5
#define LOG2E 1.4426950408889634f

// ---------------- weight fp32 -> bf16 converter (runs every launch) ----------------
__global__ __launch_bounds__(256) void cvt_w(
    const float* __restrict__ a, const float* __restrict__ b, const float* __restrict__ c,
    const float* __restrict__ d, const float* __restrict__ e, unsigned short* __restrict__ o)
{
    int i = (blockIdx.x * 256 + threadIdx.x) * 4;
    if (i >= WB_ELEMS) return;
    const float* s; int off;
    if (i < O_KV)      { s = a; off = i - O_QKV; }
    else if (i < O_M1) { s = b; off = i - O_KV; }
    else if (i < O_M2) { s = c; off = i - O_M1; }
    else if (i < O_PW) { s = d; off = i - O_M2; }
    else               { s = e; off = i - O_PW; }
    float4 v = *(const float4*)(s + off);
    u16x4 r;
    r[0] = f2b(v.x); r[1] = f2b(v.y); r[2] = f2b(v.z); r[3] = f2b(v.w);
    *(u16x4*)(o + i) = r;
}

template<bool WB>
DEVINL s16x8 loadB(const unsigned short* wbp, const float* wfp, int off) {
    if constexpr (WB) {
        return *(const s16x8*)(wbp + off);
    } else {
        float4 v0 = *(const float4*)(wfp + off);
        float4 v1 = *(const float4*)(wfp + off + 4);
        s16x8 r;
        r[0] = (short)f2b(v0.x); r[1] = (short)f2b(v0.y); r[2] = (short)f2b(v0.z); r[3] = (short)f2b(v0.w);
        r[4] = (short)f2b(v1.x); r[5] = (short)f2b(v1.y); r[6] = (short)f2b(v1.z); r[7] = (short)f2b(v1.w);
        return r;
    }
}

template<bool WB>
__global__ __launch_bounds__(512, 2) void swin_fused(
    const float* __restrict__ x,
    const float* __restrict__ y,
    const float* __restrict__ mask_x,
    const float* __restrict__ mask_y,
    const float* __restrict__ qkv_w,
    const float* __restrict__ qkv_b,
    const float* __restrict__ kv_w,
    const float* __restrict__ kv_b,
    const float* __restrict__ rpb_x,
    const float* __restrict__ rpb_y,
    const float* __restrict__ m1w,
    const float* __restrict__ m1b,
    const float* __restrict__ m2w,
    const float* __restrict__ m2b,
    const float* __restrict__ pw,
    const float* __restrict__ pb,
    const int* __restrict__ rel_idx,
    const unsigned short* __restrict__ wb,   // bf16 weight cache (valid iff WB)
    float* __restrict__ out)
{
    __shared__ __align__(16) unsigned short smem[SMEM_ELEMS];

    const int tid  = threadIdx.x;
    const int w    = tid >> 6;          // wave 0..7
    const int lane = tid & 63;
    const int l16  = lane & 15;
    const int quad = lane >> 4;
    const int wn   = w & 3;             // GEMM N-quarter
    const int wm   = w >> 2;            // GEMM window (0/1)
    const int win  = w >> 2;            // attn window (0/1)
    const int rb   = w & 3;             // attn row-block (16 rows within window)
    const int b    = blockIdx.x;        // window-pair 0..1023

    const unsigned short* wqkv = WB ? wb + O_QKV : nullptr;
    const unsigned short* wkv  = WB ? wb + O_KV  : nullptr;
    const unsigned short* wm1  = WB ? wb + O_M1  : nullptr;
    const unsigned short* wm2  = WB ? wb + O_M2  : nullptr;
    const unsigned short* wpw  = WB ? wb + O_PW  : nullptr;

    // ---------------- stage x (2 windows, contiguous) -> R1 ----------------
    {
        const float4* gx = (const float4*)(x + (size_t)b * 128 * 192);
        #pragma unroll
        for (int it = 0; it < 6; ++it) {
            int c = it * 512 + tid;                // 8-elem chunk, 3072 total
            int e = c * 8;
            int row = e / 192, col = e - row * 192;
            float4 v0 = gx[c * 2], v1 = gx[c * 2 + 1];
            u16x8 r;
            r[0] = f2b(v0.x); r[1] = f2b(v0.y); r[2] = f2b(v0.z); r[3] = f2b(v0.w);
            r[4] = f2b(v1.x); r[5] = f2b(v1.y); r[6] = f2b(v1.z); r[7] = f2b(v1.w);
            *(u16x8*)&smem[OFF_R1 + row * LD_IN + col] = r;
        }
    }
    __syncthreads();   // B1: x staged

    // ---------------- GEMM1: QKV = x @ qkv_w^T + b  (both windows) ----------------
    {
        s16x8 afr[4][6];
        #pragma unroll
        for (int mt = 0; mt < 4; ++mt)
            #pragma unroll
            for (int ks = 0; ks < 6; ++ks)
                afr[mt][ks] = *(const s16x8*)&smem[OFF_R1 + (wm * 64 + mt * 16 + l16) * LD_IN + ks * 32 + quad * 8];
        __syncthreads();   // B1b: x-fragments in regs -> R1 reusable for Q

        #pragma unroll
        for (int nt = 0; nt < 9; ++nt) {
            int n0  = wn * 144 + nt * 16;
            int col = n0 + l16;
            f32x4 a0 = {0,0,0,0}, a1 = {0,0,0,0}, a2 = {0,0,0,0}, a3 = {0,0,0,0};
            #pragma unroll
            for (int ks = 0; ks < 6; ++ks) {
                s16x8 bf = loadB<WB>(wqkv, qkv_w, col * 192 + ks * 32 + quad * 8);
                a0 = mfma16(afr[0][ks], bf, a0);
                a1 = mfma16(afr[1][ks], bf, a1);
                a2 = mfma16(afr[2][ks], bf, a2);
                a3 = mfma16(afr[3][ks], bf, a3);
            }
            f32x4 accv[4] = {a0, a1, a2, a3};
            float bias = qkv_b[col];
            if (n0 < 192) {           // Q (scaled) -> R1
                #pragma unroll
                for (int mt = 0; mt < 4; ++mt)
                    #pragma unroll
                    for (int r = 0; r < 4; ++r)
                        smem[OFF_R1 + (wm * 64 + mt * 16 + quad * 4 + r) * LD_K + col] =
                            f2b((accv[mt][r] + bias) * SCALE);
            } else if (n0 < 384) {    // K -> R2
                #pragma unroll
                for (int mt = 0; mt < 4; ++mt)
                    #pragma unroll
                    for (int r = 0; r < 4; ++r)
                        smem[OFF_R2 + (wm * 64 + mt * 16 + quad * 4 + r) * LD_K + (col - 192)] =
                            f2b(accv[mt][r] + bias);
            } else {                  // V -> V^T[d][tok] per window -> R3
                #pragma unroll
                for (int mt = 0; mt < 4; ++mt)
                    #pragma unroll
                    for (int r = 0; r < 4; ++r)
                        smem[OFF_R3 + wm * VT_WIN + (col - 384) * LD_VT + (mt * 16 + quad * 4 + r)] =
                            f2b(accv[mt][r] + bias);
            }
        }
    }
    __syncthreads();   // B2: Q,K,VT visible

    // ---------------- hoist Q fragments (6 heads, shared by both attns) ----------------
    s16x8 aQ[6];
    #pragma unroll
    for (int h = 0; h < 6; ++h)
        aQ[h] = *(const s16x8*)&smem[OFF_R1 + (win * 64 + rb * 16 + l16) * LD_K + h * 32 + quad * 8];
    __syncthreads();   // B2b: Q in regs -> R1 reusable for P

    // ---------------- attention (wave: 16 rows of its window, all 6 heads) ----------------
    auto do_attn = [&](const float* __restrict__ rpb,
                       const float* __restrict__ mask,
                       unsigned (&opk)[24]) {
        int widx = (b * 2 + win) & 1023;
        unsigned idxp[8];
        #pragma unroll
        for (int p = 0; p < 8; ++p) {
            int ntt = p >> 1, r0 = (p & 1) * 2;
            int row = rb * 16 + quad * 4;
            int col = ntt * 16 + l16;
            unsigned lo = (unsigned)rel_idx[(row + r0)     * 64 + col] * 6u;
            unsigned hi = (unsigned)rel_idx[(row + r0 + 1) * 64 + col] * 6u;
            idxp[p] = lo | (hi << 16);
        }
        const float* mrow = mask + (size_t)widx * 4096 + (rb * 16 + quad * 4) * 64 + l16;
        const int pbase = OFF_R1 + w * 16 * LD_P;
        #pragma unroll
        for (int h = 0; h < 6; ++h) {
            f32x4 sacc[4];
            #pragma unroll
            for (int ntt = 0; ntt < 4; ++ntt) {
                s16x8 bK = *(const s16x8*)&smem[OFF_R2 + (win * 64 + ntt * 16 + l16) * LD_K + h * 32 + quad * 8];
                f32x4 z = {0,0,0,0};
                sacc[ntt] = mfma16(aQ[h], bK, z);
            }
            float sv[4][4];
            #pragma unroll
            for (int ntt = 0; ntt < 4; ++ntt)
                #pragma unroll
                for (int r = 0; r < 4; ++r) {
                    unsigned idx6 = (idxp[ntt * 2 + (r >> 1)] >> ((r & 1) * 16)) & 0xFFFFu;
                    sv[ntt][r] = sacc[ntt][r] + rpb[idx6 + h] + mrow[r * 64 + ntt * 16];
                }
            float pv[4][4];
            #pragma unroll
            for (int r = 0; r < 4; ++r) {
                float mx = fmaxf(fmaxf(sv[0][r], sv[1][r]), fmaxf(sv[2][r], sv[3][r]));
                mx = fmaxf(mx, __shfl_xor(mx, 1));
                mx = fmaxf(mx, __shfl_xor(mx, 2));
                mx = fmaxf(mx, __shfl_xor(mx, 4));
                mx = fmaxf(mx, __shfl_xor(mx, 8));
                float e0 = __builtin_amdgcn_exp2f((sv[0][r] - mx) * LOG2E);
                float e1 = __builtin_amdgcn_exp2f((sv[1][r] - mx) * LOG2E);
                float e2 = __builtin_amdgcn_exp2f((sv[2][r] - mx) * LOG2E);
                float e3 = __builtin_amdgcn_exp2f((sv[3][r] - mx) * LOG2E);
                float s = e0 + e1 + e2 + e3;
                s += __shfl_xor(s, 1);
                s += __shfl_xor(s, 2);
                s += __shfl_xor(s, 4);
                s += __shfl_xor(s, 8);
                float inv = __builtin_amdgcn_rcpf(s);
                pv[0][r] = e0 * inv; pv[1][r] = e1 * inv; pv[2][r] = e2 * inv; pv[3][r] = e3 * inv;
            }
            #pragma unroll
            for (int ntt = 0; ntt < 4; ++ntt)
                #pragma unroll
                for (int r = 0; r < 4; ++r)
                    smem[pbase + (quad * 4 + r) * LD_P + ntt * 16 + l16] = f2b(pv[ntt][r]);
            f32x4 oh0 = {0,0,0,0}, oh1 = {0,0,0,0};
            #pragma unroll
            for (int kt = 0; kt < 2; ++kt) {
                s16x8 aP  = *(const s16x8*)&smem[pbase + l16 * LD_P + kt * 32 + quad * 8];
                s16x8 bV0 = *(const s16x8*)&smem[OFF_R3 + win * VT_WIN + (h * 32 + l16) * LD_VT + kt * 32 + quad * 8];
                s16x8 bV1 = *(const s16x8*)&smem[OFF_R3 + win * VT_WIN + (h * 32 + 16 + l16) * LD_VT + kt * 32 + quad * 8];
                oh0 = mfma16(aP, bV0, oh0);
                oh1 = mfma16(aP, bV1, oh1);
            }
            #pragma unroll
            for (int r = 0; r < 4; ++r)
                opk[h * 4 + r] = (unsigned)f2b(oh0[r]) | ((unsigned)f2b(oh1[r]) << 16);
        }
    };

    unsigned opks[24];
    do_attn(rpb_x, mask_x, opks);
    __syncthreads();   // B3: attn1 done -> R1 reusable for y

    // ---------------- stage y (2 windows) -> R1 ----------------
    {
        const float4* gy = (const float4*)(y + (size_t)b * 128 * 192);
        #pragma unroll
        for (int it = 0; it < 6; ++it) {
            int c = it * 512 + tid;
            int e = c * 8;
            int row = e / 192, col = e - row * 192;
            float4 v0 = gy[c * 2], v1 = gy[c * 2 + 1];
            u16x8 r;
            r[0] = f2b(v0.x); r[1] = f2b(v0.y); r[2] = f2b(v0.z); r[3] = f2b(v0.w);
            r[4] = f2b(v1.x); r[5] = f2b(v1.y); r[6] = f2b(v1.z); r[7] = f2b(v1.w);
            *(u16x8*)&smem[OFF_R1 + row * LD_IN + col] = r;
        }
    }
    __syncthreads();   // B3b: y staged

    // ---------------- GEMM1b: KV2 = y @ kv_w^T + b (both windows) ----------------
    {
        s16x8 afr[4][6];
        #pragma unroll
        for (int mt = 0; mt < 4; ++mt)
            #pragma unroll
            for (int ks = 0; ks < 6; ++ks)
                afr[mt][ks] = *(const s16x8*)&smem[OFF_R1 + (wm * 64 + mt * 16 + l16) * LD_IN + ks * 32 + quad * 8];

        #pragma unroll
        for (int nt = 0; nt < 6; ++nt) {
            int n0  = wn * 96 + nt * 16;
            int col = n0 + l16;
            f32x4 a0 = {0,0,0,0}, a1 = {0,0,0,0}, a2 = {0,0,0,0}, a3 = {0,0,0,0};
            #pragma unroll
            for (int ks = 0; ks < 6; ++ks) {
                s16x8 bf = loadB<WB>(wkv, kv_w, col * 192 + ks * 32 + quad * 8);
                a0 = mfma16(afr[0][ks], bf, a0);
                a1 = mfma16(afr[1][ks], bf, a1);
                a2 = mfma16(afr[2][ks], bf, a2);
                a3 = mfma16(afr[3][ks], bf, a3);
            }
            f32x4 accv[4] = {a0, a1, a2, a3};
            float bias = kv_b[col];
            if (n0 < 192) {           // K2 overwrites K (R2)
                #pragma unroll
                for (int mt = 0; mt < 4; ++mt)
                    #pragma unroll
                    for (int r = 0; r < 4; ++r)
                        smem[OFF_R2 + (wm * 64 + mt * 16 + quad * 4 + r) * LD_K + col] =
                            f2b(accv[mt][r] + bias);
            } else {                  // V2 -> V2^T overwrites VT (R3)
                #pragma unroll
                for (int mt = 0; mt < 4; ++mt)
                    #pragma unroll
                    for (int r = 0; r < 4; ++r)
                        smem[OFF_R3 + wm * VT_WIN + (col - 192) * LD_VT + (mt * 16 + quad * 4 + r)] =
                            f2b(accv[mt][r] + bias);
            }
        }
    }
    __syncthreads();   // B4: K2,V2T visible; y reads done -> R1 reusable for P

    unsigned opkc[24];
    do_attn(rpb_y, mask_y, opkc);
    __syncthreads();   // B5: attn2 done -> R2/R3 dead -> CAT writable

    // ---------------- CAT = [x_self | x_cross] (128x392 over R2+R3) ----------------
    #pragma unroll
    for (int h = 0; h < 6; ++h) {
        #pragma unroll
        for (int r = 0; r < 4; ++r) {
            int row = win * 64 + rb * 16 + quad * 4 + r;
            unsigned ps = opks[h * 4 + r];
            unsigned pc = opkc[h * 4 + r];
            smem[CATB + row * LD_CAT + h * 32 + l16]             = (unsigned short)(ps & 0xFFFFu);
            smem[CATB + row * LD_CAT + h * 32 + 16 + l16]        = (unsigned short)(ps >> 16);
            smem[CATB + row * LD_CAT + 192 + h * 32 + l16]       = (unsigned short)(pc & 0xFFFFu);
            smem[CATB + row * LD_CAT + 192 + h * 32 + 16 + l16]  = (unsigned short)(pc >> 16);
        }
    }
    __syncthreads();   // B6

    // ---------------- merge1 + leaky_relu -> M1 (R1) ----------------
    // ks-outer: acc[3 nt][4 mt] live (48), cat frags (32) + bf (8) transient
    {
        f32x4 acc[3][4];
        #pragma unroll
        for (int nt = 0; nt < 3; ++nt)
            #pragma unroll
            for (int mt = 0; mt < 4; ++mt) { f32x4 z = {0,0,0,0}; acc[nt][mt] = z; }
        #pragma unroll
        for (int ks = 0; ks < 12; ++ks) {
            s16x8 cm[4];
            #pragma unroll
            for (int mt = 0; mt < 4; ++mt)
                cm[mt] = *(const s16x8*)&smem[CATB + (wm * 64 + mt * 16 + l16) * LD_CAT + ks * 32 + quad * 8];
            #pragma unroll
            for (int nt = 0; nt < 3; ++nt) {
                int col = wn * 48 + nt * 16 + l16;
                s16x8 bf = loadB<WB>(wm1, m1w, col * 384 + ks * 32 + quad * 8);
                #pragma unroll
                for (int mt = 0; mt < 4; ++mt)
                    acc[nt][mt] = mfma16(cm[mt], bf, acc[nt][mt]);
            }
        }
        #pragma unroll
        for (int nt = 0; nt < 3; ++nt) {
            int col = wn * 48 + nt * 16 + l16;
            float bias = m1b[col];
            #pragma unroll
            for (int mt = 0; mt < 4; ++mt)
                #pragma unroll
                for (int r = 0; r < 4; ++r) {
                    float v = acc[nt][mt][r] + bias;
                    v = (v > 0.f) ? v : 0.2f * v;
                    smem[OFF_R1 + (wm * 64 + mt * 16 + quad * 4 + r) * LD_M + col] = f2b(v);
                }
        }
    }
    __syncthreads();   // B7

    // ---------------- merge2 -> M2 (R2; CAT dead) ----------------
    {
        s16x8 afr[4][6];
        #pragma unroll
        for (int mt = 0; mt < 4; ++mt)
            #pragma unroll
            for (int ks = 0; ks < 6; ++ks)
                afr[mt][ks] = *(const s16x8*)&smem[OFF_R1 + (wm * 64 + mt * 16 + l16) * LD_M + ks * 32 + quad * 8];

        #pragma unroll
        for (int nt = 0; nt < 3; ++nt) {
            int col = wn * 48 + nt * 16 + l16;
            f32x4 a0 = {0,0,0,0}, a1 = {0,0,0,0}, a2 = {0,0,0,0}, a3 = {0,0,0,0};
            #pragma unroll
            for (int ks = 0; ks < 6; ++ks) {
                s16x8 bf = loadB<WB>(wm2, m2w, col * 192 + ks * 32 + quad * 8);
                a0 = mfma16(afr[0][ks], bf, a0);
                a1 = mfma16(afr[1][ks], bf, a1);
                a2 = mfma16(afr[2][ks], bf, a2);
                a3 = mfma16(afr[3][ks], bf, a3);
            }
            f32x4 accv[4] = {a0, a1, a2, a3};
            float bias = m2b[col];
            #pragma unroll
            for (int mt = 0; mt < 4; ++mt)
                #pragma unroll
                for (int r = 0; r < 4; ++r)
                    smem[OFF_R2 + (wm * 64 + mt * 16 + quad * 4 + r) * LD_M + col] = f2b(accv[mt][r] + bias);
        }
    }
    __syncthreads();   // B8

    // ---------------- proj -> out (fp32) ----------------
    {
        s16x8 afr[4][6];
        #pragma unroll
        for (int mt = 0; mt < 4; ++mt)
            #pragma unroll
            for (int ks = 0; ks < 6; ++ks)
                afr[mt][ks] = *(const s16x8*)&smem[OFF_R2 + (wm * 64 + mt * 16 + l16) * LD_M + ks * 32 + quad * 8];

        #pragma unroll
        for (int nt = 0; nt < 3; ++nt) {
            int col = wn * 48 + nt * 16 + l16;
            f32x4 a0 = {0,0,0,0}, a1 = {0,0,0,0}, a2 = {0,0,0,0}, a3 = {0,0,0,0};
            #pragma unroll
            for (int ks = 0; ks < 6; ++ks) {
                s16x8 bf = loadB<WB>(wpw, pw, col * 192 + ks * 32 + quad * 8);
                a0 = mfma16(afr[0][ks], bf, a0);
                a1 = mfma16(afr[1][ks], bf, a1);
                a2 = mfma16(afr[2][ks], bf, a2);
                a3 = mfma16(afr[3][ks], bf, a3);
            }
            f32x4 accv[4] = {a0, a1, a2, a3};
            float bias = pb[col];
            #pragma unroll
            for (int mt = 0; mt < 4; ++mt)
                #pragma unroll
                for (int r = 0; r < 4; ++r) {
                    int row = wm * 64 + mt * 16 + quad * 4 + r;
                    out[((size_t)b * 128 + row) * 192 + col] = accv[mt][r] + bias;
                }
        }
    }
}

extern "C" void kernel_launch(void* const* d_in, const int* in_sizes, int n_in,
                              void* d_out, int out_size, void* d_ws, size_t ws_size,
                              hipStream_t stream) {
    (void)in_sizes; (void)n_in; (void)out_size;
    const float* x    = (const float*)d_in[0];
    const float* y    = (const float*)d_in[1];
    const float* mx   = (const float*)d_in[2];
    const float* my   = (const float*)d_in[3];
    const float* qw   = (const float*)d_in[4];
    const float* qb   = (const float*)d_in[5];
    const float* kw   = (const float*)d_in[6];
    const float* kb   = (const float*)d_in[7];
    const float* rx   = (const float*)d_in[8];
    const float* ry   = (const float*)d_in[9];
    const float* m1w  = (const float*)d_in[10];
    const float* m1b  = (const float*)d_in[11];
    const float* m2w  = (const float*)d_in[12];
    const float* m2b  = (const float*)d_in[13];
    const float* pw   = (const float*)d_in[14];
    const float* pb   = (const float*)d_in[15];
    const int*   ridx = (const int*)d_in[16];
    float* out = (float*)d_out;

    if (ws_size >= (size_t)WB_BYTES) {
        unsigned short* wbuf = (unsigned short*)d_ws;
        cvt_w<<<WB_ELEMS / 4 / 256, 256, 0, stream>>>(qw, kw, m1w, m2w, pw, wbuf);
        swin_fused<true><<<1024, 512, 0, stream>>>(
            x, y, mx, my, qw, qb, kw, kb, rx, ry, m1w, m1b, m2w, m2b, pw, pb, ridx,
            wbuf, out);
    } else {
        swin_fused<false><<<1024, 512, 0, stream>>>(
            x, y, mx, my, qw, qb, kw, kb, rx, ry, m1w, m1b, m2w, m2b, pw, pb, ridx,
            nullptr, out);
    }
}